// Round 11
// baseline (54.639 us; speedup 1.0000x reference)
//
#include <hip/hip_runtime.h>

// DCNv2 fused: deformable im2col + f16 MFMA GEMM.
// R11: L2-traffic cut. 256Co x 256pix tiles (1024 thr, 16 waves = 4M x 4N),
//      A staged via LDS (no dup), K-split x4 (grid 256), K32 steps (NS=18).
//      Traffic 590 -> ~375 MB. f16 partials + fused reduce.
// ws: [0, 8388608)            xt  = x transposed to (n, hw, C) f16
//     [8388608, 9568256)      wt3 = weight tiled [q][f][r][kq] f16
//     [9568256, +4*8388608)   parts[4] = k-quarter partial sums f16

typedef _Float16 f16x8 __attribute__((ext_vector_type(8)));
typedef _Float16 f16x4 __attribute__((ext_vector_type(4)));
typedef float f32x4 __attribute__((ext_vector_type(4)));

#define C_IN 256
#define CO   256
#define KK   9
#define HWSZ 4096
#define LDB  40                 // LDS row stride (elems): 32 + 8 pad (80 B)
#define BUFB (256 * LDB)        // one B tile: 256 pix rows
#define BUFA (256 * LDB)        // one A tile: 256 rows (16 frag x 16)
#define PSTR (4 * CO * HWSZ)    // elems per partial

struct __align__(16) SPX { ushort4 cell; f16x4 w; };   // 16 B

static __device__ __forceinline__ f16x8 splat8(_Float16 v) {
    f16x8 r = {v, v, v, v, v, v, v, v};
    return r;
}

// ---- transpose x: (N,C,64,64) f32 -> xt[n][p][c] f16 ----
__global__ void transpose_x_kernel(const float* __restrict__ x,
                                   _Float16* __restrict__ xt) {
    __shared__ float tile[64][65];
    const int n  = blockIdx.z;
    const int p0 = blockIdx.x * 64;
    const int c0 = blockIdx.y * 64;
    const int tx = threadIdx.x & 63;
    const int ty = threadIdx.x >> 6;
    for (int i = 0; i < 16; ++i) {
        int c = ty * 16 + i;
        tile[c][tx] = x[((size_t)(n * C_IN + c0 + c) << 12) + p0 + tx];
    }
    __syncthreads();
    for (int i = 0; i < 16; ++i) {
        int p = ty * 16 + i;
        xt[((size_t)((n << 12) + p0 + p) << 8) + c0 + tx] = (_Float16)tile[tx][p];
    }
}

// ---- weight: (Co,C,3,3) f32 -> wt3[((q*16+f)*16+r)*32+kq] f16 ----
// q = (c>>5)*9 + kk (step-major!), f = o>>4, r = o&15, kq = c&31.
// Per K32-step: 16 KB contiguous block, fragment f at +f*1024.
__global__ void transpose_w_kernel(const float* __restrict__ w,
                                   _Float16* __restrict__ wt3) {
    const int o = blockIdx.x;
    const int c = threadIdx.x;
    const int f = o >> 4, r = o & 15, cc = c >> 5, kq = c & 31;
    for (int kk = 0; kk < KK; ++kk) {
        int q = cc * 9 + kk;
        wt3[((q * 16 + f) * 16 + r) * 32 + kq] =
            (_Float16)w[(o * C_IN + c) * KK + kk];
    }
}

// ---- fused main: block = 256 Co x 256 pix x K/NQ, 1024 thr (16 waves) ----
template <int NQ>
__launch_bounds__(1024, 1)
__global__ void dcn_main_kernel(const float* __restrict__ offset,
                                const float* __restrict__ mask,
                                const float* __restrict__ bias,
                                const _Float16* __restrict__ xt,
                                const _Float16* __restrict__ wt3,
                                float* __restrict__ out,
                                _Float16* __restrict__ parts) {
    constexpr int NS = 72 / NQ;          // K32 steps per block
    __shared__ SPX sP[2304];             // 256 pix x 9 taps (36 KB)
    __shared__ _Float16 sB[2 * BUFB];    // B tiles (40 KB)
    __shared__ _Float16 sA[2 * BUFA];    // A tiles (40 KB)

    const int tid = threadIdx.x;
    const int nwg = 64 * NQ;
    const int cpx = nwg >> 3;
    const int lin = blockIdx.x;
    const int id  = (lin & 7) * cpx + (lin >> 3);   // XCD-contiguous
    const int quarter = (NQ > 1) ? (id >> 6) : 0;
    const int pt   = id & 63;            // pixel tile 0..63 (256 pix each)
    const int p0   = pt * 256;
    const int n    = p0 >> 12;
    const int phw0 = p0 & 4095;
    const int q0   = quarter * NS;       // first q (cc*9+k) of this block

    // --- precompute bilinear params: 256 pixels x 9 taps ---
    for (int t = tid; t < 2304; t += 1024) {
        int pl = t / 9;
        int k  = t - pl * 9;
        int phw = phw0 + pl;
        int h = phw >> 6, w = phw & 63;
        float dy = offset[(size_t)(n * 18 + 2 * k)     * HWSZ + phw];
        float dx = offset[(size_t)(n * 18 + 2 * k + 1) * HWSZ + phw];
        float mv = mask  [(size_t)(n * 9 + k)          * HWSZ + phw];
        float py = dy + (float)(h - 1 + k / 3);
        float px = dx + (float)(w - 1 + k % 3);
        float y0f = floorf(py), x0f = floorf(px);
        int y0 = (int)y0f, x0 = (int)x0f;
        float wy1 = py - y0f, wx1 = px - x0f;
        float wy0 = 1.f - wy1, wx0 = 1.f - wx1;
        int y1 = y0 + 1, x1 = x0 + 1;
        float vy0 = (y0 >= 0 && y0 < 64) ? 1.f : 0.f;
        float vy1 = (y1 >= 0 && y1 < 64) ? 1.f : 0.f;
        float vx0 = (x0 >= 0 && x0 < 64) ? 1.f : 0.f;
        float vx1 = (x1 >= 0 && x1 < 64) ? 1.f : 0.f;
        int cy0 = min(max(y0, 0), 63), cy1 = min(max(y1, 0), 63);
        int cx0 = min(max(x0, 0), 63), cx1 = min(max(x1, 0), 63);
        SPX e;
        e.cell = make_ushort4((unsigned short)(cy0 * 64 + cx0),
                              (unsigned short)(cy0 * 64 + cx1),
                              (unsigned short)(cy1 * 64 + cx0),
                              (unsigned short)(cy1 * 64 + cx1));
        f16x4 wv;
        wv.x = (_Float16)(wy0 * wx0 * mv * vy0 * vx0);
        wv.y = (_Float16)(wy0 * wx1 * mv * vy0 * vx1);
        wv.z = (_Float16)(wy1 * wx0 * mv * vy1 * vx0);
        wv.w = (_Float16)(wy1 * wx1 * mv * vy1 * vx1);
        e.w = wv;
        sP[t] = e;
    }
    __syncthreads();

    const int lane = tid & 63;
    const int wid  = tid >> 6;    // 0..15
    const int m    = wid >> 2;    // M slab (64 Co)
    const int nq   = wid & 3;     // N slab (64 pix)
    const int l15  = lane & 15;
    const int lhi  = lane >> 4;

    const int spix = tid >> 2;    // staging pixel 0..255
    const int oct  = tid & 3;     // staging c-octet
    const int spix9 = spix * 9;

    const char* xb   = (const char*)(xt + ((size_t)n << 12) * C_IN);
    const char* wt3b = (const char*)wt3 + ((size_t)q0 << 14);  // step s at +s*16KB

    const int vWe = spix * LDB + oct * 8;            // B-write elem offset
    const int aWe = (tid >> 2) * LDB + (tid & 3) * 8;// A-write elem offset
    // consumer read bases (elems)
    const int vBe = (nq * 64 + l15) * LDB + lhi * 8;       // + fn*16*LDB
    const int aBe = (m * 64 + l15) * LDB + lhi * 8;        // + fm*16*LDB

    f16x8 ga[4];       // gather corners (in-step lifetime)
    uint4 areg;        // A stage (in-step lifetime)
    f16x4 gw;
    f32x4 acc[4][4];
    for (int i = 0; i < 4; ++i)
        for (int j = 0; j < 4; ++j)
            acc[i][j] = (f32x4){0.f, 0.f, 0.f, 0.f};

// step T: tap = (q0+T)%9 = T%9 (q0 multiple of 9 when NQ|8... general: use full q)
#define ISSUE_GA(T)                                                           \
    {                                                                         \
        const SPX e_ = sP[spix9 + (q0 + (T)) % 9];                            \
        gw = e_.w;                                                            \
        const unsigned c_ = (unsigned)(((q0 + (T)) / 9) * 64 + oct * 16);     \
        ga[0] = *(const f16x8*)(xb + (((unsigned)e_.cell.x << 9) + c_));      \
        ga[1] = *(const f16x8*)(xb + (((unsigned)e_.cell.y << 9) + c_));      \
        ga[2] = *(const f16x8*)(xb + (((unsigned)e_.cell.z << 9) + c_));      \
        ga[3] = *(const f16x8*)(xb + (((unsigned)e_.cell.w << 9) + c_));      \
    }

#define ISSUE_AL(T)                                                           \
    { areg = *(const uint4*)(wt3b + (((size_t)(T)) << 14) + tid * 16); }

#define COMBINE(BUF)                                                          \
    {                                                                         \
        f16x8 r_ = ga[0] * splat8(gw.x) + ga[1] * splat8(gw.y)                \
                 + ga[2] * splat8(gw.z) + ga[3] * splat8(gw.w);               \
        *(f16x8*)(&sB[(BUF) * BUFB + vWe]) = r_;                              \
    }

#define AWRITE(BUF)                                                           \
    { *(uint4*)(&sA[(BUF) * BUFA + aWe]) = areg; }

#define MFMA_STEP(BUF)                                                        \
    {                                                                         \
        const _Float16* ab_ = &sA[(BUF) * BUFA] + aBe;                        \
        const _Float16* bb_ = &sB[(BUF) * BUFB] + vBe;                        \
        f16x8 af_[4];                                                         \
        for (int fm_ = 0; fm_ < 4; ++fm_)                                     \
            af_[fm_] = *(const f16x8*)(ab_ + fm_ * 16 * LDB);                 \
        __builtin_amdgcn_s_setprio(1);                                        \
        for (int fn_ = 0; fn_ < 4; ++fn_) {                                   \
            f16x8 b_ = *(const f16x8*)(bb_ + fn_ * 16 * LDB);                 \
            for (int fm_ = 0; fm_ < 4; ++fm_)                                 \
                acc[fm_][fn_] = __builtin_amdgcn_mfma_f32_16x16x32_f16(       \
                    af_[fm_], b_, acc[fm_][fn_], 0, 0, 0);                    \
        }                                                                     \
        __builtin_amdgcn_s_setprio(0);                                        \
    }

#define BAR()                                                                 \
    {                                                                         \
        asm volatile("s_waitcnt lgkmcnt(0)" ::: "memory");                    \
        __builtin_amdgcn_s_barrier();                                         \
        asm volatile("" ::: "memory");                                        \
    }

    // prologue: stage step 0 into buf 0
    ISSUE_AL(0)
    ISSUE_GA(0)
    COMBINE(0)
    AWRITE(0)
    BAR()

#pragma unroll
    for (int s = 0; s < NS; ++s) {
        if (s + 1 < NS) {
            ISSUE_AL(s + 1)               // 1 load/thread
            ISSUE_GA(s + 1)               // 4 loads/thread, fly over MFMA
        }
        __builtin_amdgcn_sched_barrier(0);
        MFMA_STEP(s & 1)                  // LDS-only; no vmcnt dependence
        if (s + 1 < NS) {
            COMBINE((s + 1) & 1)          // waits gathers (~full MFMA later)
            AWRITE((s + 1) & 1)
            BAR()
        }
    }

    // --- epilogue: C/D layout col=lane&15 (pix), row=(lane>>4)*4+r (o) ---
    if constexpr (NQ > 1) {
        _Float16* pp = parts + (size_t)quarter * PSTR;
        for (int fm = 0; fm < 4; ++fm)
            for (int fn = 0; fn < 4; ++fn) {
                int pix = phw0 + nq * 64 + fn * 16 + l15;
                for (int r = 0; r < 4; ++r) {
                    int o = m * 64 + fm * 16 + lhi * 4 + r;
                    pp[((size_t)(n * CO + o) << 12) + pix] =
                        (_Float16)acc[fm][fn][r];
                }
            }
    } else {
        for (int fm = 0; fm < 4; ++fm)
            for (int fn = 0; fn < 4; ++fn) {
                int pix = phw0 + nq * 64 + fn * 16 + l15;
                for (int r = 0; r < 4; ++r) {
                    int o = m * 64 + fm * 16 + lhi * 4 + r;
                    out[((size_t)(n * CO + o) << 12) + pix] =
                        acc[fm][fn][r] + bias[o];
                }
            }
    }
#undef ISSUE_GA
#undef ISSUE_AL
#undef COMBINE
#undef AWRITE
#undef MFMA_STEP
#undef BAR
}

// ---- reduce: out = sum(parts[0..3]) + bias ----
__global__ void reduce_kernel(float* __restrict__ out,
                              const _Float16* __restrict__ parts,
                              const float* __restrict__ bias, int n8) {
    int i = blockIdx.x * blockDim.x + threadIdx.x;
    if (i >= n8) return;
    f16x8 a = ((const f16x8*)parts)[i];
    f16x8 b = ((const f16x8*)(parts + (size_t)PSTR))[i];
    f16x8 c = ((const f16x8*)(parts + 2 * (size_t)PSTR))[i];
    f16x8 d = ((const f16x8*)(parts + 3 * (size_t)PSTR))[i];
    float bv = bias[((i * 8) >> 12) & 255];
    f32x4 r0, r1;
    for (int e = 0; e < 4; ++e)
        r0[e] = (float)a[e] + (float)b[e] + (float)c[e] + (float)d[e] + bv;
    for (int e = 0; e < 4; ++e)
        r1[e] = (float)a[e+4] + (float)b[e+4] + (float)c[e+4] + (float)d[e+4] + bv;
    ((f32x4*)out)[2 * i]     = r0;
    ((f32x4*)out)[2 * i + 1] = r1;
}

extern "C" void kernel_launch(void* const* d_in, const int* in_sizes, int n_in,
                              void* d_out, int out_size, void* d_ws, size_t ws_size,
                              hipStream_t stream) {
    const float* x      = (const float*)d_in[0];
    const float* offset = (const float*)d_in[1];
    const float* mask   = (const float*)d_in[2];
    const float* weight = (const float*)d_in[3];
    const float* bias   = (const float*)d_in[4];
    float* out = (float*)d_out;

    _Float16* xt  = (_Float16*)d_ws;
    _Float16* wt3 = (_Float16*)((char*)d_ws + 8388608);
    _Float16* parts = (_Float16*)((char*)d_ws + 9568256);
    const bool split = ws_size >= (size_t)9568256 + (size_t)4 * PSTR * 2;

    transpose_x_kernel<<<dim3(64, 4, 4), 256, 0, stream>>>(x, xt);
    transpose_w_kernel<<<CO, C_IN, 0, stream>>>(weight, wt3);
    if (split) {
        dcn_main_kernel<4><<<dim3(256), 1024, 0, stream>>>(offset, mask, bias,
                                                           xt, wt3, out, parts);
        reduce_kernel<<<dim3(PSTR / 8 / 256), 256, 0, stream>>>(out, parts, bias,
                                                                PSTR / 8);
    } else {
        dcn_main_kernel<1><<<dim3(64), 1024, 0, stream>>>(offset, mask, bias,
                                                          xt, wt3, out, parts);
    }
}